// Round 2
// baseline (470.631 us; speedup 1.0000x reference)
//
#include <hip/hip_runtime.h>
#include <hip/hip_bf16.h>

// SigmaMoE: out[t,:] = sum_e sigmoid(x_t . es_e) * relu(x_t @ K_e) @ V_e
// B=4 S=4096 D=1024 E=16 H=128  -> two GEMMs:
//   GEMM1: scores[16384,2048] = relu(Xb @ Kall) * sel   (K=1024)
//   GEMM2: out[16384,1024]    = scores @ Vall           (K=2048)
// Both GEMMs consume B^T-layout weights staged as bf16 in d_ws.

typedef __attribute__((ext_vector_type(8))) short bf16x8;
typedef __attribute__((ext_vector_type(4))) float f32x4;

#define D_MODEL 1024
#define NTOK    16384
#define NEXP    16
#define HEXP    128
#define NEH     2048

__device__ __forceinline__ unsigned short f2b(float f) {
  union { float f; unsigned u; } c; c.f = f;
  unsigned u = c.u;
  return (unsigned short)((u + 0x7FFFu + ((u >> 16) & 1u)) >> 16);
}

__device__ __forceinline__ void gload16(const void* g, void* l) {
  __builtin_amdgcn_global_load_lds(
      (const __attribute__((address_space(1))) void*)g,
      (__attribute__((address_space(3))) void*)l,
      16, 0, 0);
}

// ---- conversion kernels -------------------------------------------------

__global__ void cvt_x_kernel(const float4* __restrict__ x, ushort4* __restrict__ o) {
  int i = blockIdx.x * 256 + threadIdx.x;
  float4 v = x[i];
  ushort4 r;
  r.x = f2b(v.x); r.y = f2b(v.y); r.z = f2b(v.z); r.w = f2b(v.w);
  o[i] = r;
}

// keys [E][D][H] -> Kt[(e*128+h)][d]  (B^T for GEMM1)
__global__ void cvt_keys_kernel(const float* __restrict__ k, unsigned short* __restrict__ kt) {
  int idx = blockIdx.x * 256 + threadIdx.x;       // over NEH*D_MODEL
  int d  = idx & 1023;
  int eh = idx >> 10;
  int h  = eh & 127;
  int e  = eh >> 7;
  kt[idx] = f2b(k[(e << 17) + (d << 7) + h]);
}

// values [E][H][D] -> Vt[d][(e*128+h)]  (B^T for GEMM2: rows are output dim d)
__global__ void cvt_vals_kernel(const float* __restrict__ v, unsigned short* __restrict__ vt) {
  int idx = blockIdx.x * 256 + threadIdx.x;       // over D_MODEL*NEH
  int eh = idx & 2047;
  int d  = idx >> 11;
  int e  = eh >> 7;
  int h  = eh & 127;
  vt[idx] = f2b(v[(e << 17) + (h << 10) + d]);
}

// sel[t][e] = sigmoid(x_t . es_e), fp32 exact inputs
__global__ void sel_kernel(const float* __restrict__ x, const float* __restrict__ es,
                           float* __restrict__ sel) {
  int tok = blockIdx.x * 16 + (threadIdx.x >> 4);
  int e   = threadIdx.x & 15;
  const float4* xr = (const float4*)(x + (size_t)tok * D_MODEL);
  const float4* er = (const float4*)(es + (size_t)e * D_MODEL);
  float acc = 0.f;
#pragma unroll 4
  for (int i = 0; i < D_MODEL / 4; ++i) {
    float4 a = xr[i];
    float4 b = er[i];
    acc += a.x * b.x + a.y * b.y + a.z * b.z + a.w * b.w;
  }
  sel[tok * NEXP + e] = 1.f / (1.f + __expf(-acc));
}

// ---- 128x128 bf16 GEMM (m97 structure), B^T input ----------------------
// EPI==0: out = bf16( relu(acc) * sel[row][bcol>>7] )   (scores)
// EPI==1: out = fp32 acc                                 (final)
template <int EPI>
__global__ __launch_bounds__(256, 3)
void gemm_bt(const unsigned short* __restrict__ A, const unsigned short* __restrict__ Bt,
             int K, int N, const float* __restrict__ sel,
             unsigned short* __restrict__ outB, float* __restrict__ outF) {
  __shared__ unsigned short As[128 * 64];
  __shared__ unsigned short Bs[128 * 64];

  const int tid  = threadIdx.x;
  const int wave = tid >> 6;
  const int lane = tid & 63;
  const int brow = blockIdx.x * 128;
  const int bcol = blockIdx.y * 128;
  const int wr = (wave >> 1) * 64;   // wave row offset in tile
  const int wc = (wave & 1) * 64;    // wave col offset in tile
  const int lr = lane & 15;
  const int lk = (lane >> 4) * 8;

  f32x4 acc[4][4] = {};

  // staging addresses: thread t covers LDS bytes [w*1024 + l*16] of each 4KB chunk
  const unsigned short* aPtr = A + (size_t)(brow + (tid >> 3)) * K + (tid & 7) * 8;
  const unsigned short* bPtr = Bt + (size_t)(bcol + (tid >> 3)) * K + (tid & 7) * 8;
  char* asW = (char*)As + (wave << 10);
  char* bsW = (char*)Bs + (wave << 10);

  for (int k0 = 0; k0 < K; k0 += 64) {
#pragma unroll
    for (int i = 0; i < 4; ++i) {
      gload16(aPtr + (size_t)i * 32 * K, asW + i * 4096);
      gload16(bPtr + (size_t)i * 32 * K, bsW + i * 4096);
    }
    aPtr += 64;
    bPtr += 64;
    __syncthreads();   // drains vmcnt -> LDS tiles visible
#pragma unroll
    for (int kk = 0; kk < 2; ++kk) {
      bf16x8 a[4], b[4];
#pragma unroll
      for (int m = 0; m < 4; ++m)
        a[m] = *(const bf16x8*)&As[(wr + m * 16 + lr) * 64 + kk * 32 + lk];
#pragma unroll
      for (int n = 0; n < 4; ++n)
        b[n] = *(const bf16x8*)&Bs[(wc + n * 16 + lr) * 64 + kk * 32 + lk];
#pragma unroll
      for (int m = 0; m < 4; ++m)
#pragma unroll
        for (int n = 0; n < 4; ++n)
          acc[m][n] = __builtin_amdgcn_mfma_f32_16x16x32_bf16(a[m], b[n], acc[m][n], 0, 0, 0);
    }
    __syncthreads();   // all waves done reading before next stage
  }

  const int r0 = brow + wr + (lane >> 4) * 4;
  const int c0 = bcol + wc + lr;

  if (EPI == 0) {
    const int e = bcol >> 7;  // BN==128 == expert width, so one expert per block-col
#pragma unroll
    for (int m = 0; m < 4; ++m) {
#pragma unroll
      for (int j = 0; j < 4; ++j) {
        const int r = r0 + m * 16 + j;
        const float s = sel[r * NEXP + e];
#pragma unroll
        for (int n = 0; n < 4; ++n) {
          float v = acc[m][n][j];
          v = v > 0.f ? v * s : 0.f;
          outB[(size_t)r * N + c0 + n * 16] = f2b(v);
        }
      }
    }
  } else {
#pragma unroll
    for (int m = 0; m < 4; ++m) {
#pragma unroll
      for (int j = 0; j < 4; ++j) {
        const int r = r0 + m * 16 + j;
#pragma unroll
        for (int n = 0; n < 4; ++n)
          outF[(size_t)r * N + c0 + n * 16] = acc[m][n][j];
      }
    }
  }
}

// ---- launch -------------------------------------------------------------

extern "C" void kernel_launch(void* const* d_in, const int* in_sizes, int n_in,
                              void* d_out, int out_size, void* d_ws, size_t ws_size,
                              hipStream_t stream) {
  const float* X  = (const float*)d_in[0];   // [4,4096,1024]
  const float* ES = (const float*)d_in[1];   // [16,1024]
  const float* Kw = (const float*)d_in[2];   // [16,1024,128]
  const float* Vw = (const float*)d_in[3];   // [16,128,1024]
  float* out = (float*)d_out;                // [4,4096,1024] fp32

  char* ws = (char*)d_ws;
  unsigned short* Xb = (unsigned short*)ws; ws += (size_t)NTOK * D_MODEL * 2;   // 32 MB
  unsigned short* Sc = (unsigned short*)ws; ws += (size_t)NTOK * NEH * 2;       // 64 MB
  unsigned short* Kt = (unsigned short*)ws; ws += (size_t)NEH * D_MODEL * 2;    // 4 MB
  unsigned short* Vt = (unsigned short*)ws; ws += (size_t)D_MODEL * NEH * 2;    // 4 MB
  float*          Sl = (float*)ws;          ws += (size_t)NTOK * NEXP * 4;      // 1 MB

  cvt_x_kernel<<<NTOK * D_MODEL / 4 / 256, 256, 0, stream>>>((const float4*)X, (ushort4*)Xb);
  cvt_keys_kernel<<<NEH * D_MODEL / 256, 256, 0, stream>>>(Kw, Kt);
  cvt_vals_kernel<<<D_MODEL * NEH / 256, 256, 0, stream>>>(Vw, Vt);
  sel_kernel<<<NTOK / 16, 256, 0, stream>>>(X, ES, Sl);

  dim3 g1(NTOK / 128, NEH / 128);      // (128, 16)
  gemm_bt<0><<<g1, 256, 0, stream>>>(Xb, Kt, D_MODEL, NEH, Sl, Sc, nullptr);

  dim3 g2(NTOK / 128, D_MODEL / 128);  // (128, 8)
  gemm_bt<1><<<g2, 256, 0, stream>>>(Sc, Vt, NEH, D_MODEL, nullptr, nullptr, out);
}

// Round 3
// 344.891 us; speedup vs baseline: 1.3646x; 1.3646x over previous
//
#include <hip/hip_runtime.h>
#include <hip/hip_bf16.h>

// SigmaMoE: out[t,:] = sum_e sigmoid(x_t . es_e) * relu(x_t @ K_e) @ V_e
// B=4 S=4096 D=1024 E=16 H=128  -> two GEMMs:
//   GEMM1: scores[16384,2048] = relu(Xb @ Kall) * sel   (K=1024)
//   GEMM2: out[16384,1024]    = scores @ Vall           (K=2048)
// Router sel = sigmoid(Xb @ ESb^T) is itself a skinny MFMA GEMM (N=16).

typedef __attribute__((ext_vector_type(8))) short bf16x8;
typedef __attribute__((ext_vector_type(4))) float f32x4;

#define D_MODEL 1024
#define NTOK    16384
#define NEXP    16
#define HEXP    128
#define NEH     2048

__device__ __forceinline__ unsigned short f2b(float f) {
  union { float f; unsigned u; } c; c.f = f;
  unsigned u = c.u;
  return (unsigned short)((u + 0x7FFFu + ((u >> 16) & 1u)) >> 16);
}

__device__ __forceinline__ void gload16(const void* g, void* l) {
  __builtin_amdgcn_global_load_lds(
      (const __attribute__((address_space(1))) void*)g,
      (__attribute__((address_space(3))) void*)l,
      16, 0, 0);
}

// ---- conversion kernels -------------------------------------------------

__global__ void cvt_x_kernel(const float4* __restrict__ x, ushort4* __restrict__ o) {
  int i = blockIdx.x * 256 + threadIdx.x;
  float4 v = x[i];
  ushort4 r;
  r.x = f2b(v.x); r.y = f2b(v.y); r.z = f2b(v.z); r.w = f2b(v.w);
  o[i] = r;
}

// expert_sel [E][D] -> bf16 (row-major, already B^T layout for the router GEMM)
__global__ void cvt_es_kernel(const float4* __restrict__ es, ushort4* __restrict__ o) {
  int i = blockIdx.x * 256 + threadIdx.x;    // over E*D/4 = 4096
  float4 v = es[i];
  ushort4 r;
  r.x = f2b(v.x); r.y = f2b(v.y); r.z = f2b(v.z); r.w = f2b(v.w);
  o[i] = r;
}

// keys [E][D][H] -> Kt[(e*128+h)][d]  (B^T for GEMM1)
__global__ void cvt_keys_kernel(const float* __restrict__ k, unsigned short* __restrict__ kt) {
  int idx = blockIdx.x * 256 + threadIdx.x;       // over NEH*D_MODEL
  int d  = idx & 1023;
  int eh = idx >> 10;
  int h  = eh & 127;
  int e  = eh >> 7;
  kt[idx] = f2b(k[(e << 17) + (d << 7) + h]);
}

// values [E][H][D] -> Vt[d][(e*128+h)]  (B^T for GEMM2: rows are output dim d)
__global__ void cvt_vals_kernel(const float* __restrict__ v, unsigned short* __restrict__ vt) {
  int idx = blockIdx.x * 256 + threadIdx.x;       // over D_MODEL*NEH
  int eh = idx & 2047;
  int d  = idx >> 11;
  int e  = eh >> 7;
  int h  = eh & 127;
  vt[idx] = f2b(v[(e << 17) + (h << 10) + d]);
}

// ---- router: sel[t][e] = sigmoid(Xb @ ESb^T), one 16x16 tile per wave ---
// Wave w of block b handles tokens [b*64 + w*16, +16), all 16 experts.
// A-frag: Xb rows (tokens); B-frag: ESb rows (experts). fp32 accum, fused
// sigmoid. Operands read straight from global: Xb is L3-resident (32 MB),
// ESb is 32 KB (L2-hot). 32 serial MFMAs/wave, grid = 256 blocks = 1/CU.
__global__ __launch_bounds__(256)
void sel_mfma_kernel(const unsigned short* __restrict__ Xb,
                     const unsigned short* __restrict__ ESb,
                     float* __restrict__ sel) {
  const int wave = threadIdx.x >> 6;
  const int lane = threadIdx.x & 63;
  const int tk = blockIdx.x * 64 + wave * 16;
  const int lr = lane & 15;
  const int hk = (lane >> 4) * 8;

  const unsigned short* a0 = Xb + (size_t)(tk + lr) * D_MODEL + hk;
  const unsigned short* b0 = ESb + (size_t)lr * D_MODEL + hk;

  f32x4 acc = {};
#pragma unroll
  for (int k0 = 0; k0 < D_MODEL; k0 += 32) {
    bf16x8 a = *(const bf16x8*)(a0 + k0);
    bf16x8 b = *(const bf16x8*)(b0 + k0);
    acc = __builtin_amdgcn_mfma_f32_16x16x32_bf16(a, b, acc, 0, 0, 0);
  }

  const int r0 = tk + (lane >> 4) * 4;   // token (A-dim) ; expert col = lr (B-dim)
#pragma unroll
  for (int j = 0; j < 4; ++j)
    sel[(size_t)(r0 + j) * NEXP + lr] = 1.f / (1.f + __expf(-acc[j]));
}

// ---- 128x128 bf16 GEMM (m97 structure), B^T input ----------------------
// EPI==0: out = bf16( relu(acc) * sel[row][bcol>>7] )   (scores)
// EPI==1: out = fp32 acc                                 (final)
template <int EPI>
__global__ __launch_bounds__(256, 3)
void gemm_bt(const unsigned short* __restrict__ A, const unsigned short* __restrict__ Bt,
             int K, int N, const float* __restrict__ sel,
             unsigned short* __restrict__ outB, float* __restrict__ outF) {
  __shared__ unsigned short As[128 * 64];
  __shared__ unsigned short Bs[128 * 64];

  const int tid  = threadIdx.x;
  const int wave = tid >> 6;
  const int lane = tid & 63;
  const int brow = blockIdx.x * 128;
  const int bcol = blockIdx.y * 128;
  const int wr = (wave >> 1) * 64;   // wave row offset in tile
  const int wc = (wave & 1) * 64;    // wave col offset in tile
  const int lr = lane & 15;
  const int lk = (lane >> 4) * 8;

  f32x4 acc[4][4] = {};

  const unsigned short* aPtr = A + (size_t)(brow + (tid >> 3)) * K + (tid & 7) * 8;
  const unsigned short* bPtr = Bt + (size_t)(bcol + (tid >> 3)) * K + (tid & 7) * 8;
  char* asW = (char*)As + (wave << 10);
  char* bsW = (char*)Bs + (wave << 10);

  for (int k0 = 0; k0 < K; k0 += 64) {
#pragma unroll
    for (int i = 0; i < 4; ++i) {
      gload16(aPtr + (size_t)i * 32 * K, asW + i * 4096);
      gload16(bPtr + (size_t)i * 32 * K, bsW + i * 4096);
    }
    aPtr += 64;
    bPtr += 64;
    __syncthreads();   // drains vmcnt -> LDS tiles visible
#pragma unroll
    for (int kk = 0; kk < 2; ++kk) {
      bf16x8 a[4], b[4];
#pragma unroll
      for (int m = 0; m < 4; ++m)
        a[m] = *(const bf16x8*)&As[(wr + m * 16 + lr) * 64 + kk * 32 + lk];
#pragma unroll
      for (int n = 0; n < 4; ++n)
        b[n] = *(const bf16x8*)&Bs[(wc + n * 16 + lr) * 64 + kk * 32 + lk];
#pragma unroll
      for (int m = 0; m < 4; ++m)
#pragma unroll
        for (int n = 0; n < 4; ++n)
          acc[m][n] = __builtin_amdgcn_mfma_f32_16x16x32_bf16(a[m], b[n], acc[m][n], 0, 0, 0);
    }
    __syncthreads();
  }

  const int r0 = brow + wr + (lane >> 4) * 4;
  const int c0 = bcol + wc + lr;

  if (EPI == 0) {
    const int e = bcol >> 7;  // BN==128 == expert width, so one expert per block-col
#pragma unroll
    for (int m = 0; m < 4; ++m) {
#pragma unroll
      for (int j = 0; j < 4; ++j) {
        const int r = r0 + m * 16 + j;
        const float s = sel[r * NEXP + e];
#pragma unroll
        for (int n = 0; n < 4; ++n) {
          float v = acc[m][n][j];
          v = v > 0.f ? v * s : 0.f;
          outB[(size_t)r * N + c0 + n * 16] = f2b(v);
        }
      }
    }
  } else {
#pragma unroll
    for (int m = 0; m < 4; ++m) {
#pragma unroll
      for (int j = 0; j < 4; ++j) {
        const int r = r0 + m * 16 + j;
#pragma unroll
        for (int n = 0; n < 4; ++n)
          outF[(size_t)r * N + c0 + n * 16] = acc[m][n][j];
      }
    }
  }
}

// ---- launch -------------------------------------------------------------

extern "C" void kernel_launch(void* const* d_in, const int* in_sizes, int n_in,
                              void* d_out, int out_size, void* d_ws, size_t ws_size,
                              hipStream_t stream) {
  const float* X  = (const float*)d_in[0];   // [4,4096,1024]
  const float* ES = (const float*)d_in[1];   // [16,1024]
  const float* Kw = (const float*)d_in[2];   // [16,1024,128]
  const float* Vw = (const float*)d_in[3];   // [16,128,1024]
  float* out = (float*)d_out;                // [4,4096,1024] fp32

  char* ws = (char*)d_ws;
  unsigned short* Xb  = (unsigned short*)ws; ws += (size_t)NTOK * D_MODEL * 2;   // 32 MB
  unsigned short* Sc  = (unsigned short*)ws; ws += (size_t)NTOK * NEH * 2;       // 64 MB
  unsigned short* Kt  = (unsigned short*)ws; ws += (size_t)NEH * D_MODEL * 2;    // 4 MB
  unsigned short* Vt  = (unsigned short*)ws; ws += (size_t)D_MODEL * NEH * 2;    // 4 MB
  unsigned short* ESb = (unsigned short*)ws; ws += (size_t)NEXP * D_MODEL * 2;   // 32 KB
  float*          Sl  = (float*)ws;          ws += (size_t)NTOK * NEXP * 4;      // 1 MB

  cvt_x_kernel<<<NTOK * D_MODEL / 4 / 256, 256, 0, stream>>>((const float4*)X, (ushort4*)Xb);
  cvt_es_kernel<<<NEXP * D_MODEL / 4 / 256, 256, 0, stream>>>((const float4*)ES, (ushort4*)ESb);
  cvt_keys_kernel<<<NEH * D_MODEL / 256, 256, 0, stream>>>(Kw, Kt);
  cvt_vals_kernel<<<D_MODEL * NEH / 256, 256, 0, stream>>>(Vw, Vt);

  sel_mfma_kernel<<<NTOK / 64, 256, 0, stream>>>(Xb, ESb, Sl);

  dim3 g1(NTOK / 128, NEH / 128);      // (128, 16)
  gemm_bt<0><<<g1, 256, 0, stream>>>(Xb, Kt, D_MODEL, NEH, Sl, Sc, nullptr);

  dim3 g2(NTOK / 128, D_MODEL / 128);  // (128, 8)
  gemm_bt<1><<<g2, 256, 0, stream>>>(Sc, Vt, NEH, D_MODEL, nullptr, nullptr, out);
}

// Round 7
// 306.967 us; speedup vs baseline: 1.5332x; 1.1235x over previous
//
#include <hip/hip_runtime.h>
#include <hip/hip_bf16.h>

// SigmaMoE: out = sum_e sigmoid(x.es_e) * relu(x@K_e) @ V_e
//   GEMM1: scores[16384,2048] = relu(Xb @ Kall^T) * sel   (K=1024)
//   GEMM2: out[16384,1024]    = scores @ Vall^T            (K=2048)
// gemm256: 256x256 tile, 8 waves, BK=32, 3-deep LDS ring + counted vmcnt (T4),
// read-side XOR swizzle staged via pre-permuted global source (rule #21), T5.

typedef __attribute__((ext_vector_type(8))) short bf16x8;
typedef __attribute__((ext_vector_type(4))) float f32x4;

#define D_MODEL 1024
#define NTOK    16384
#define NEXP    16
#define NEH     2048

__device__ __forceinline__ unsigned short f2b(float f) {
  union { float f; unsigned u; } c; c.f = f;
  unsigned u = c.u;
  return (unsigned short)((u + 0x7FFFu + ((u >> 16) & 1u)) >> 16);
}

__device__ __forceinline__ void gload16(const void* g, void* l) {
  __builtin_amdgcn_global_load_lds(
      (const __attribute__((address_space(1))) void*)g,
      (__attribute__((address_space(3))) void*)l,
      16, 0, 0);
}

// ---- conversion kernels -------------------------------------------------

__global__ void cvt_x_kernel(const float4* __restrict__ x, ushort4* __restrict__ o) {
  int i = blockIdx.x * 256 + threadIdx.x;
  float4 v = x[i];
  ushort4 r;
  r.x = f2b(v.x); r.y = f2b(v.y); r.z = f2b(v.z); r.w = f2b(v.w);
  o[i] = r;
}

__global__ void cvt_es_kernel(const float4* __restrict__ es, ushort4* __restrict__ o) {
  int i = blockIdx.x * 256 + threadIdx.x;
  float4 v = es[i];
  ushort4 r;
  r.x = f2b(v.x); r.y = f2b(v.y); r.z = f2b(v.z); r.w = f2b(v.w);
  o[i] = r;
}

// keys [E][D][H] -> Kt[(e*128+h)][d]
__global__ void cvt_keys_kernel(const float* __restrict__ k, unsigned short* __restrict__ kt) {
  int idx = blockIdx.x * 256 + threadIdx.x;
  int d  = idx & 1023;
  int eh = idx >> 10;
  int h  = eh & 127;
  int e  = eh >> 7;
  kt[idx] = f2b(k[(e << 17) + (d << 7) + h]);
}

// values [E][H][D] -> Vt[d][(e*128+h)]
__global__ void cvt_vals_kernel(const float* __restrict__ v, unsigned short* __restrict__ vt) {
  int idx = blockIdx.x * 256 + threadIdx.x;
  int eh = idx & 2047;
  int d  = idx >> 11;
  int e  = eh >> 7;
  int h  = eh & 127;
  vt[idx] = f2b(v[(e << 17) + (h << 10) + d]);
}

// ---- router: sel = sigmoid(Xb @ ESb^T), one 16x16 MFMA tile per wave ----
__global__ __launch_bounds__(256)
void sel_mfma_kernel(const unsigned short* __restrict__ Xb,
                     const unsigned short* __restrict__ ESb,
                     float* __restrict__ sel) {
  const int wave = threadIdx.x >> 6;
  const int lane = threadIdx.x & 63;
  const int tk = blockIdx.x * 64 + wave * 16;
  const int lr = lane & 15;
  const int hk = (lane >> 4) * 8;

  const unsigned short* a0 = Xb + (size_t)(tk + lr) * D_MODEL + hk;
  const unsigned short* b0 = ESb + (size_t)lr * D_MODEL + hk;

  f32x4 acc = {};
#pragma unroll
  for (int k0 = 0; k0 < D_MODEL; k0 += 32) {
    bf16x8 a = *(const bf16x8*)(a0 + k0);
    bf16x8 b = *(const bf16x8*)(b0 + k0);
    acc = __builtin_amdgcn_mfma_f32_16x16x32_bf16(a, b, acc, 0, 0, 0);
  }

  const int r0 = tk + (lane >> 4) * 4;
#pragma unroll
  for (int j = 0; j < 4; ++j)
    sel[(size_t)(r0 + j) * NEXP + lr] = 1.f / (1.f + __expf(-acc[j]));
}

// ---- 256x256 bf16 GEMM, 3-deep ring, counted vmcnt ----------------------
// LDS ring: 3 bufs x 32KB { A[256][32] @0, B[256][32] @16384 }, rows 64B,
// 16B groups within a row stored at gslot = g ^ (row&3)  (read-conflict 8->4way).
// Schedule per iter t: STAGE(t+2 -> buf[(t+2)%3]); vmcnt(8); barrier;
//   12x ds_read_b128; 32x MFMA (setprio 1); lgkmcnt(0); barrier.
// Safety: WAR - buf[(t+2)%3] last read at iter t-1, freed by its end barrier.
//         RAW - vmcnt(8) leaves only tiles {t+1,t+2} (8 loads) in flight.
// Tail: iter nt-2 -> vmcnt(4), iter nt-1 -> vmcnt(0). Prologue stages 2 tiles.
template <int EPI>
__global__ __launch_bounds__(512, 2)
void gemm256(const unsigned short* __restrict__ A, const unsigned short* __restrict__ Bt,
             int K, int N, const float* __restrict__ sel,
             unsigned short* __restrict__ outB, float* __restrict__ outF) {
  __shared__ char lds[3 * 32768];

  const int tid  = threadIdx.x;
  const int wave = tid >> 6;
  const int lane = tid & 63;
  const int wrow = wave >> 2;      // 0..1  (128 rows each)
  const int wcol = wave & 3;       // 0..3  (64 cols each)
  const int lr   = lane & 15;
  const int brow = blockIdx.x << 8;
  const int bcol = blockIdx.y << 8;

  // staging: slot s = j*512 + tid covers LDS bytes [s*16, +16) of a 16KB tile
  // (row = s>>2, gslot = s&3); source fetches logical group g = gslot ^ (row&3).
  const int r0 = tid >> 2,          g0 = (tid & 3) ^ (r0 & 3);
  const int r1 = (512 + tid) >> 2,  g1 = (tid & 3) ^ (r1 & 3);
  const unsigned short* aS0 = A  + (size_t)(brow + r0) * K + g0 * 8;
  const unsigned short* aS1 = A  + (size_t)(brow + r1) * K + g1 * 8;
  const unsigned short* bS0 = Bt + (size_t)(bcol + r0) * K + g0 * 8;
  const unsigned short* bS1 = Bt + (size_t)(bcol + r1) * K + g1 * 8;
  const int dW = wave << 10;       // wave-uniform LDS dest; HW adds lane*16

  // fragment read offsets (same XOR on the read side)
  const int swz = (((lane >> 4) ^ (lr & 3)) << 4);
  int aOff[8], bOff[4];
#pragma unroll
  for (int m = 0; m < 8; ++m)
    aOff[m] = (wrow * 128 + m * 16 + lr) * 64 + swz;
#pragma unroll
  for (int n = 0; n < 4; ++n)
    bOff[n] = 16384 + (wcol * 64 + n * 16 + lr) * 64 + swz;

  f32x4 acc[8][4] = {};
  const int nt = K >> 5;

#define STAGEK(t, b) {                                          \
    char* base_ = lds + (b) * 32768;                            \
    gload16(aS0 + (size_t)(t) * 32, base_ + dW);                \
    gload16(aS1 + (size_t)(t) * 32, base_ + 8192 + dW);         \
    gload16(bS0 + (size_t)(t) * 32, base_ + 16384 + dW);        \
    gload16(bS1 + (size_t)(t) * 32, base_ + 24576 + dW);        \
  }

  STAGEK(0, 0);
  STAGEK(1, 1);

  int cur = 0, stg = 2;
  for (int t = 0; t < nt; ++t) {
    if (t + 2 < nt) {
      STAGEK(t + 2, stg);
      asm volatile("s_waitcnt vmcnt(8)" ::: "memory");
    } else if (t + 2 == nt) {
      asm volatile("s_waitcnt vmcnt(4)" ::: "memory");
    } else {
      asm volatile("s_waitcnt vmcnt(0)" ::: "memory");
    }
    __builtin_amdgcn_s_barrier();
    asm volatile("" ::: "memory");

    const char* buf = lds + cur * 32768;
    bf16x8 a[8], b[4];
#pragma unroll
    for (int m = 0; m < 8; ++m) a[m] = *(const bf16x8*)(buf + aOff[m]);
#pragma unroll
    for (int n = 0; n < 4; ++n) b[n] = *(const bf16x8*)(buf + bOff[n]);

    __builtin_amdgcn_s_setprio(1);
#pragma unroll
    for (int m = 0; m < 8; ++m)
#pragma unroll
      for (int n = 0; n < 4; ++n)
        acc[m][n] = __builtin_amdgcn_mfma_f32_16x16x32_bf16(a[m], b[n], acc[m][n], 0, 0, 0);
    __builtin_amdgcn_s_setprio(0);

    asm volatile("s_waitcnt lgkmcnt(0)" ::: "memory");
    __builtin_amdgcn_s_barrier();
    cur = (cur == 2) ? 0 : cur + 1;
    stg = (stg == 2) ? 0 : stg + 1;
  }
#undef STAGEK

  // epilogue: wave's 128x64 sub-tile
  const int rb = brow + wrow * 128 + ((lane >> 4) << 2);
  const int cb = bcol + (wcol << 6) + lr;

  if (EPI == 0) {
    const int e = (bcol >> 7) + (wcol >> 1);   // wave-uniform expert index
#pragma unroll
    for (int m = 0; m < 8; ++m) {
#pragma unroll
      for (int j = 0; j < 4; ++j) {
        const int r = rb + m * 16 + j;
        const float s = sel[(size_t)r * NEXP + e];
#pragma unroll
        for (int n = 0; n < 4; ++n) {
          float v = acc[m][n][j];
          v = v > 0.f ? v * s : 0.f;
          outB[(size_t)r * N + cb + n * 16] = f2b(v);
        }
      }
    }
  } else {
#pragma unroll
    for (int m = 0; m < 8; ++m) {
#pragma unroll
      for (int j = 0; j < 4; ++j) {
        const int r = rb + m * 16 + j;
#pragma unroll
        for (int n = 0; n < 4; ++n)
          outF[(size_t)r * N + cb + n * 16] = acc[m][n][j];
      }
    }
  }
}

// ---- launch -------------------------------------------------------------

extern "C" void kernel_launch(void* const* d_in, const int* in_sizes, int n_in,
                              void* d_out, int out_size, void* d_ws, size_t ws_size,
                              hipStream_t stream) {
  const float* X  = (const float*)d_in[0];   // [4,4096,1024]
  const float* ES = (const float*)d_in[1];   // [16,1024]
  const float* Kw = (const float*)d_in[2];   // [16,1024,128]
  const float* Vw = (const float*)d_in[3];   // [16,128,1024]
  float* out = (float*)d_out;                // [4,4096,1024] fp32

  char* ws = (char*)d_ws;
  unsigned short* Xb  = (unsigned short*)ws; ws += (size_t)NTOK * D_MODEL * 2;   // 32 MB
  unsigned short* Sc  = (unsigned short*)ws; ws += (size_t)NTOK * NEH * 2;       // 64 MB
  unsigned short* Kt  = (unsigned short*)ws; ws += (size_t)NEH * D_MODEL * 2;    // 4 MB
  unsigned short* Vt  = (unsigned short*)ws; ws += (size_t)D_MODEL * NEH * 2;    // 4 MB
  unsigned short* ESb = (unsigned short*)ws; ws += (size_t)NEXP * D_MODEL * 2;   // 32 KB
  float*          Sl  = (float*)ws;          ws += (size_t)NTOK * NEXP * 4;      // 1 MB

  cvt_x_kernel<<<NTOK * D_MODEL / 4 / 256, 256, 0, stream>>>((const float4*)X, (ushort4*)Xb);
  cvt_es_kernel<<<NEXP * D_MODEL / 4 / 256, 256, 0, stream>>>((const float4*)ES, (ushort4*)ESb);
  cvt_keys_kernel<<<NEH * D_MODEL / 256, 256, 0, stream>>>(Kw, Kt);
  cvt_vals_kernel<<<D_MODEL * NEH / 256, 256, 0, stream>>>(Vw, Vt);

  sel_mfma_kernel<<<NTOK / 64, 256, 0, stream>>>(Xb, ESb, Sl);

  dim3 g1(NTOK / 256, NEH / 256);      // (64, 8)
  gemm256<0><<<g1, 512, 0, stream>>>(Xb, Kt, D_MODEL, NEH, Sl, Sc, nullptr);

  dim3 g2(NTOK / 256, D_MODEL / 256);  // (64, 4)
  gemm256<1><<<g2, 512, 0, stream>>>(Sc, Vt, NEH, D_MODEL, nullptr, nullptr, out);
}

// Round 10
// 298.548 us; speedup vs baseline: 1.5764x; 1.0282x over previous
//
#include <hip/hip_runtime.h>
#include <hip/hip_bf16.h>

// SigmaMoE: out = sum_e sigmoid(x.es_e) * relu(x@K_e) @ V_e
//   GEMM1: scores[16384,2048] = relu(Xb @ Kall^T) * sel   (K=1024)
//   GEMM2: out[16384,1024]    = scores @ Vall^T            (K=2048)
// gemm256: 256x256 tile, 8 waves, BK=32, 3-deep LDS ring + counted vmcnt (T4).
// Swizzle key r&3 -> (r>>1)&3: bank(r,s)=(r*16+s*4)%32 has period 2 in r, so
// the old key collapsed 16 lanes onto 4 bank-quads (4-way); new key spreads
// them over all 32 banks (2-way = b128 floor, free per m136).

typedef __attribute__((ext_vector_type(8))) short bf16x8;
typedef __attribute__((ext_vector_type(4))) float f32x4;

#define D_MODEL 1024
#define NTOK    16384
#define NEXP    16
#define NEH     2048

__device__ __forceinline__ unsigned short f2b(float f) {
  union { float f; unsigned u; } c; c.f = f;
  unsigned u = c.u;
  return (unsigned short)((u + 0x7FFFu + ((u >> 16) & 1u)) >> 16);
}

__device__ __forceinline__ void gload16(const void* g, void* l) {
  __builtin_amdgcn_global_load_lds(
      (const __attribute__((address_space(1))) void*)g,
      (__attribute__((address_space(3))) void*)l,
      16, 0, 0);
}

// ---- conversion kernels -------------------------------------------------

__global__ void cvt_x_kernel(const float4* __restrict__ x, ushort4* __restrict__ o) {
  int i = blockIdx.x * 256 + threadIdx.x;
  float4 v = x[i];
  ushort4 r;
  r.x = f2b(v.x); r.y = f2b(v.y); r.z = f2b(v.z); r.w = f2b(v.w);
  o[i] = r;
}

__global__ void cvt_es_kernel(const float4* __restrict__ es, ushort4* __restrict__ o) {
  int i = blockIdx.x * 256 + threadIdx.x;
  float4 v = es[i];
  ushort4 r;
  r.x = f2b(v.x); r.y = f2b(v.y); r.z = f2b(v.z); r.w = f2b(v.w);
  o[i] = r;
}

// keys [E][D][H] -> Kt[(e*128+h)][d]
__global__ void cvt_keys_kernel(const float* __restrict__ k, unsigned short* __restrict__ kt) {
  int idx = blockIdx.x * 256 + threadIdx.x;
  int d  = idx & 1023;
  int eh = idx >> 10;
  int h  = eh & 127;
  int e  = eh >> 7;
  kt[idx] = f2b(k[(e << 17) + (d << 7) + h]);
}

// values [E][H][D] -> Vt[d][(e*128+h)]
__global__ void cvt_vals_kernel(const float* __restrict__ v, unsigned short* __restrict__ vt) {
  int idx = blockIdx.x * 256 + threadIdx.x;
  int eh = idx & 2047;
  int d  = idx >> 11;
  int e  = eh >> 7;
  int h  = eh & 127;
  vt[idx] = f2b(v[(e << 17) + (h << 10) + d]);
}

// ---- router: sel = sigmoid(Xb @ ESb^T), 4 waves split K=1024 ------------
// Block = 16 tokens x 16 experts; wave w computes the K=[w*256,+256) partial
// via 8 MFMAs, partials reduced through LDS. Grid 1024 -> 16 waves/CU (was 4).
__global__ __launch_bounds__(256)
void sel_mfma_kernel(const unsigned short* __restrict__ Xb,
                     const unsigned short* __restrict__ ESb,
                     float* __restrict__ sel) {
  __shared__ float red[4][16][16];
  const int wave = threadIdx.x >> 6;
  const int lane = threadIdx.x & 63;
  const int tk = blockIdx.x * 16;
  const int lr = lane & 15;
  const int hk = (lane >> 4) * 8;

  const unsigned short* a0 = Xb + (size_t)(tk + lr) * D_MODEL + wave * 256 + hk;
  const unsigned short* b0 = ESb + (size_t)lr * D_MODEL + wave * 256 + hk;

  f32x4 acc = {};
#pragma unroll
  for (int k0 = 0; k0 < 256; k0 += 32) {
    bf16x8 a = *(const bf16x8*)(a0 + k0);
    bf16x8 b = *(const bf16x8*)(b0 + k0);
    acc = __builtin_amdgcn_mfma_f32_16x16x32_bf16(a, b, acc, 0, 0, 0);
  }

  const int r0 = (lane >> 4) * 4;
#pragma unroll
  for (int j = 0; j < 4; ++j) red[wave][r0 + j][lr] = acc[j];
  __syncthreads();
  if (wave == 0) {
#pragma unroll
    for (int j = 0; j < 4; ++j) {
      float s = red[0][r0 + j][lr] + red[1][r0 + j][lr]
              + red[2][r0 + j][lr] + red[3][r0 + j][lr];
      sel[(size_t)(tk + r0 + j) * NEXP + lr] = 1.f / (1.f + __expf(-s));
    }
  }
}

// ---- 256x256 bf16 GEMM, 3-deep ring, counted vmcnt ----------------------
// LDS ring: 3 bufs x 32KB { A[256][32] @0, B[256][32] @16384 }, rows 64B,
// 16B groups stored at gslot = g ^ ((row>>1)&3)  (2-way banks = b128 floor).
// Schedule per iter t: STAGE(t+2 -> buf[(t+2)%3]); vmcnt(8); barrier;
//   12x ds_read_b128; 32x MFMA (setprio 1); lgkmcnt(0); barrier.
// Safety: WAR - buf[(t+2)%3] last read at iter t-1, freed by its end barrier.
//         RAW - vmcnt(8) leaves only tiles {t+1,t+2} (8 loads) in flight.
// Tail: iter nt-2 -> vmcnt(4), iter nt-1 -> vmcnt(0). Prologue stages 2 tiles.
template <int EPI>
__global__ __launch_bounds__(512, 2)
void gemm256(const unsigned short* __restrict__ A, const unsigned short* __restrict__ Bt,
             int K, int N, const float* __restrict__ sel,
             unsigned short* __restrict__ outB, float* __restrict__ outF) {
  __shared__ char lds[3 * 32768];

  const int tid  = threadIdx.x;
  const int wave = tid >> 6;
  const int lane = tid & 63;
  const int wrow = wave >> 2;      // 0..1  (128 rows each)
  const int wcol = wave & 3;       // 0..3  (64 cols each)
  const int lr   = lane & 15;
  const int brow = blockIdx.x << 8;
  const int bcol = blockIdx.y << 8;

  // staging: slot s = j*512 + tid covers LDS bytes [s*16, +16) of a 16KB tile
  // (row = s>>2, gslot = s&3); source fetches logical group g = gslot ^ ((row>>1)&3).
  // Key identical for rows r0 and r0+128, so one g serves both halves.
  const int r0 = tid >> 2;
  const int r1 = 128 + r0;
  const int g  = (tid & 3) ^ ((tid >> 3) & 3);
  const unsigned short* aS0 = A  + (size_t)(brow + r0) * K + g * 8;
  const unsigned short* aS1 = A  + (size_t)(brow + r1) * K + g * 8;
  const unsigned short* bS0 = Bt + (size_t)(bcol + r0) * K + g * 8;
  const unsigned short* bS1 = Bt + (size_t)(bcol + r1) * K + g * 8;
  const int dW = wave << 10;       // wave-uniform LDS dest; HW adds lane*16

  // fragment read offsets (same XOR on the read side; (row>>1)&3 == (lr>>1)&3
  // for all fragment rows since m*16, wrow*128, wcol*64 are 0 mod 8)
  const int swz = (((lane >> 4) ^ ((lr >> 1) & 3)) << 4);
  int aOff[8], bOff[4];
#pragma unroll
  for (int m = 0; m < 8; ++m)
    aOff[m] = (wrow * 128 + m * 16 + lr) * 64 + swz;
#pragma unroll
  for (int n = 0; n < 4; ++n)
    bOff[n] = 16384 + (wcol * 64 + n * 16 + lr) * 64 + swz;

  f32x4 acc[8][4] = {};
  const int nt = K >> 5;

#define STAGEK(t, b) {                                          \
    char* base_ = lds + (b) * 32768;                            \
    gload16(aS0 + (size_t)(t) * 32, base_ + dW);                \
    gload16(aS1 + (size_t)(t) * 32, base_ + 8192 + dW);         \
    gload16(bS0 + (size_t)(t) * 32, base_ + 16384 + dW);        \
    gload16(bS1 + (size_t)(t) * 32, base_ + 24576 + dW);        \
  }

  STAGEK(0, 0);
  STAGEK(1, 1);

  int cur = 0, stg = 2;
  for (int t = 0; t < nt; ++t) {
    if (t + 2 < nt) {
      STAGEK(t + 2, stg);
      asm volatile("s_waitcnt vmcnt(8)" ::: "memory");
    } else if (t + 2 == nt) {
      asm volatile("s_waitcnt vmcnt(4)" ::: "memory");
    } else {
      asm volatile("s_waitcnt vmcnt(0)" ::: "memory");
    }
    __builtin_amdgcn_s_barrier();
    asm volatile("" ::: "memory");

    const char* buf = lds + cur * 32768;
    bf16x8 a[8], b[4];
#pragma unroll
    for (int m = 0; m < 8; ++m) a[m] = *(const bf16x8*)(buf + aOff[m]);
#pragma unroll
    for (int n = 0; n < 4; ++n) b[n] = *(const bf16x8*)(buf + bOff[n]);

    __builtin_amdgcn_s_setprio(1);
#pragma unroll
    for (int m = 0; m < 8; ++m)
#pragma unroll
      for (int n = 0; n < 4; ++n)
        acc[m][n] = __builtin_amdgcn_mfma_f32_16x16x32_bf16(a[m], b[n], acc[m][n], 0, 0, 0);
    __builtin_amdgcn_s_setprio(0);

    asm volatile("s_waitcnt lgkmcnt(0)" ::: "memory");
    __builtin_amdgcn_s_barrier();
    cur = (cur == 2) ? 0 : cur + 1;
    stg = (stg == 2) ? 0 : stg + 1;
  }
#undef STAGEK

  // epilogue: wave's 128x64 sub-tile
  const int rb = brow + wrow * 128 + ((lane >> 4) << 2);
  const int cb = bcol + (wcol << 6) + lr;

  if (EPI == 0) {
    const int e = (bcol >> 7) + (wcol >> 1);   // wave-uniform expert index
#pragma unroll
    for (int m = 0; m < 8; ++m) {
#pragma unroll
      for (int j = 0; j < 4; ++j) {
        const int r = rb + m * 16 + j;
        const float s = sel[(size_t)r * NEXP + e];
#pragma unroll
        for (int n = 0; n < 4; ++n) {
          float v = acc[m][n][j];
          v = v > 0.f ? v * s : 0.f;
          outB[(size_t)r * N + cb + n * 16] = f2b(v);
        }
      }
    }
  } else {
#pragma unroll
    for (int m = 0; m < 8; ++m) {
#pragma unroll
      for (int j = 0; j < 4; ++j) {
        const int r = rb + m * 16 + j;
#pragma unroll
        for (int n = 0; n < 4; ++n)
          outF[(size_t)r * N + cb + n * 16] = acc[m][n][j];
      }
    }
  }
}

// ---- launch -------------------------------------------------------------

extern "C" void kernel_launch(void* const* d_in, const int* in_sizes, int n_in,
                              void* d_out, int out_size, void* d_ws, size_t ws_size,
                              hipStream_t stream) {
  const float* X  = (const float*)d_in[0];   // [4,4096,1024]
  const float* ES = (const float*)d_in[1];   // [16,1024]
  const float* Kw = (const float*)d_in[2];   // [16,1024,128]
  const float* Vw = (const float*)d_in[3];   // [16,128,1024]
  float* out = (float*)d_out;                // [4,4096,1024] fp32

  char* ws = (char*)d_ws;
  unsigned short* Xb  = (unsigned short*)ws; ws += (size_t)NTOK * D_MODEL * 2;   // 32 MB
  unsigned short* Sc  = (unsigned short*)ws; ws += (size_t)NTOK * NEH * 2;       // 64 MB
  unsigned short* Kt  = (unsigned short*)ws; ws += (size_t)NEH * D_MODEL * 2;    // 4 MB
  unsigned short* Vt  = (unsigned short*)ws; ws += (size_t)D_MODEL * NEH * 2;    // 4 MB
  unsigned short* ESb = (unsigned short*)ws; ws += (size_t)NEXP * D_MODEL * 2;   // 32 KB
  float*          Sl  = (float*)ws;          ws += (size_t)NTOK * NEXP * 4;      // 1 MB

  cvt_x_kernel<<<NTOK * D_MODEL / 4 / 256, 256, 0, stream>>>((const float4*)X, (ushort4*)Xb);
  cvt_es_kernel<<<NEXP * D_MODEL / 4 / 256, 256, 0, stream>>>((const float4*)ES, (ushort4*)ESb);
  cvt_keys_kernel<<<NEH * D_MODEL / 256, 256, 0, stream>>>(Kw, Kt);
  cvt_vals_kernel<<<D_MODEL * NEH / 256, 256, 0, stream>>>(Vw, Vt);

  sel_mfma_kernel<<<NTOK / 16, 256, 0, stream>>>(Xb, ESb, Sl);

  dim3 g1(NTOK / 256, NEH / 256);      // (64, 8)
  gemm256<0><<<g1, 512, 0, stream>>>(Xb, Kt, D_MODEL, NEH, Sl, Sc, nullptr);

  dim3 g2(NTOK / 256, D_MODEL / 256);  // (64, 4)
  gemm256<1><<<g2, 512, 0, stream>>>(Sc, Vt, NEH, D_MODEL, nullptr, nullptr, out);
}